// Round 9
// baseline (425.123 us; speedup 1.0000x reference)
//
#include <hip/hip_runtime.h>
#include <hip/hip_bf16.h>
#include <cmath>

#define BN_EPS 1e-5f
#define SLOPE 0.2f

typedef __attribute__((ext_vector_type(8))) short bf16x8;
typedef __attribute__((ext_vector_type(4))) float f32x4;

__device__ __forceinline__ float lrelu(float x) { return x >= 0.f ? x : SLOPE * x; }
__device__ __forceinline__ float bfl(unsigned u) { return __uint_as_float(u << 16); }
__device__ __forceinline__ float bfh(unsigned u) { return __uint_as_float(u & 0xffff0000u); }
__device__ __forceinline__ float bf2f(unsigned short u) { return __uint_as_float((unsigned)u << 16); }
__device__ __forceinline__ unsigned short f2bf(float f) {
    __hip_bfloat16 h = __float2bfloat16(f);
    return *reinterpret_cast<unsigned short*>(&h);
}

// ======== CSR build via two-level bucket sort (bucket = 256 dst nodes) ========
__global__ __launch_bounds__(512) void k_hist(const int* __restrict__ ei, int E, int n,
                                              int nbk, int* __restrict__ gcnt) {
    __shared__ int h[512];
    int t = threadIdx.x;
    for (int i = t; i < nbk; i += 512) h[i] = 0;
    __syncthreads();
    int base = blockIdx.x * 8192;
    int tot = E + n;
#pragma unroll
    for (int k = 0; k < 16; ++k) {
        int i = base + k * 512 + t;
        if (i < tot) {
            int dst = (i < E) ? ei[E + i] : (i - E);
            atomicAdd(&h[dst >> 8], 1);
        }
    }
    __syncthreads();
    for (int i = t; i < nbk; i += 512)
        if (h[i]) atomicAdd(&gcnt[i], h[i]);
}

__global__ __launch_bounds__(512) void k_bscan(const int* __restrict__ gcnt,
                                               int* __restrict__ gbase,
                                               int* __restrict__ gnext, int nbk) {
    __shared__ int tmp[512];
    int t = threadIdx.x;
    int v = (t < nbk) ? gcnt[t] : 0;
    tmp[t] = v;
    __syncthreads();
    for (int off = 1; off < 512; off <<= 1) {
        int a = (t >= off) ? tmp[t - off] : 0;
        __syncthreads();
        tmp[t] += a;
        __syncthreads();
    }
    int ex = tmp[t] - v;
    if (t < nbk) { gbase[t] = ex; gnext[t] = ex; }
    if (t == nbk - 1) gbase[nbk] = tmp[t];
}

__global__ __launch_bounds__(512) void k_bucket(const int* __restrict__ ei, int E, int n,
                                                int nbk, int* __restrict__ gnext,
                                                int2* __restrict__ bbuf) {
    __shared__ int h[512], off[512];
    int t = threadIdx.x;
    for (int i = t; i < nbk; i += 512) h[i] = 0;
    __syncthreads();
    int base = blockIdx.x * 8192;
    int tot = E + n;
    int srcv[16], dstv[16], rnk[16];
#pragma unroll
    for (int k = 0; k < 16; ++k) {
        int i = base + k * 512 + t;
        dstv[k] = -1;
        if (i < tot) {
            int s, d;
            if (i < E) { s = ei[i]; d = ei[E + i]; }
            else       { s = i - E; d = s; }
            srcv[k] = s; dstv[k] = d;
            rnk[k] = atomicAdd(&h[d >> 8], 1);
        }
    }
    __syncthreads();
    for (int i = t; i < nbk; i += 512)
        if (h[i]) off[i] = atomicAdd(&gnext[i], h[i]);
    __syncthreads();
#pragma unroll
    for (int k = 0; k < 16; ++k) {
        int d = dstv[k];
        if (d >= 0)
            bbuf[off[d >> 8] + rnk[k]] = make_int2(srcv[k], d);
    }
}

// Phase 4: per-bucket counting sort -> rowp + csr + dste + layer-0 coefs
__global__ __launch_bounds__(256) void k_csr2(const int2* __restrict__ bbuf,
                                              const int* __restrict__ gbase,
                                              int* __restrict__ rowp, int* __restrict__ csr,
                                              int* __restrict__ dste,
                                              const float* __restrict__ s,
                                              const float* __restrict__ d,
                                              float* __restrict__ wv, int n, int nbk) {
    __shared__ int cnt[256], scn[256];
    int b = blockIdx.x;
    int t = threadIdx.x;
    int beg = gbase[b], end = gbase[b + 1];
    int node0 = b << 8;
    cnt[t] = 0;
    __syncthreads();
    for (int i = beg + t; i < end; i += 256)
        atomicAdd(&cnt[bbuf[i].y & 255], 1);
    __syncthreads();
    int v = cnt[t];
    scn[t] = v;
    __syncthreads();
    for (int off = 1; off < 256; off <<= 1) {
        int a = (t >= off) ? scn[t - off] : 0;
        __syncthreads();
        scn[t] += a;
        __syncthreads();
    }
    int ex = scn[t] - v;
    if (node0 + t < n) rowp[node0 + t] = beg + ex;
    if (b == nbk - 1 && t == 0) rowp[n] = end;
    cnt[t] = ex;
    __syncthreads();
    for (int i = beg + t; i < end; i += 256) {
        int2 e = bbuf[i];
        int pos = atomicAdd(&cnt[e.y & 255], 1);
        csr[beg + pos] = e.x;
        dste[beg + pos] = e.y;
        wv[beg + pos] = __expf(lrelu(s[e.x] + d[e.y]));   // layer-0 coef fused
    }
}

// ======== per-edge softmax weights (layer 1) ========
__global__ __launch_bounds__(256) void k_coef(const int* __restrict__ csr,
                                              const int* __restrict__ dste,
                                              const float* __restrict__ s,
                                              const float* __restrict__ d,
                                              float* __restrict__ wv, int tot) {
    int e4 = (blockIdx.x * 256 + threadIdx.x) * 4;
    if (e4 + 3 < tot) {
        int4 c = *(const int4*)&csr[e4];
        int4 dd = *(const int4*)&dste[e4];
        float4 w;
        w.x = __expf(lrelu(s[c.x] + d[dd.x]));
        w.y = __expf(lrelu(s[c.y] + d[dd.y]));
        w.z = __expf(lrelu(s[c.z] + d[dd.z]));
        w.w = __expf(lrelu(s[c.w] + d[dd.w]));
        *(float4*)&wv[e4] = w;
    } else {
        for (int e = e4; e < tot; ++e)
            wv[e] = __expf(lrelu(s[csr[e]] + d[dste[e]]));
    }
}

// ======== pack W0[128x128] + W1[128x64] fp32 -> bf16 B-fragment order ========
__global__ void k_packw2(const float* __restrict__ W0, const float* __restrict__ W1,
                         unsigned short* __restrict__ Wp0, unsigned short* __restrict__ Wp1) {
    int idx = blockIdx.x * 256 + threadIdx.x;
    if (idx < 128 * 128) {
        int k = idx >> 7, nG = idx & 127;
        int nt = nG >> 4, nn = nG & 15, ks = k >> 5, g = (k >> 3) & 3, j = k & 7;
        Wp0[(((nt * 4 + ks) * 64) + g * 16 + nn) * 8 + j] = f2bf(W0[idx]);
    } else {
        int i2 = idx - 128 * 128;
        if (i2 < 128 * 64) {
            int k = i2 >> 6, nG = i2 & 63;
            int nt = nG >> 4, nn = nG & 15, ks = k >> 5, g = (k >> 3) & 3, j = k & 7;
            Wp1[(((nt * 4 + ks) * 64) + g * 16 + nn) * 8 + j] = f2bf(W1[i2]);
        }
    }
}

// ======== MFMA GEMM: h = act(X)@W, bf16 h out, s/d scores fused ========
template <int CD, bool BN_IN, bool XBF>
__global__ __launch_bounds__(256) void k_gemm_mfma(
    const void* __restrict__ Xv, const unsigned short* __restrict__ Wp,
    const float* __restrict__ bnsums, const float* __restrict__ gg,
    const float* __restrict__ bb, const float* __restrict__ a_s,
    const float* __restrict__ a_d, unsigned short* __restrict__ hb,
    float* __restrict__ s_out, float* __restrict__ d_out, int n) {
    constexpr int NT = CD / 16;
    const float* Xf = (const float*)Xv;
    const unsigned short* Xh = (const unsigned short*)Xv;
    __shared__ unsigned short wl[128 * CD];
    __shared__ float sc[128], sh[128];
    int t = threadIdx.x;
    for (int i = t * 8; i < 128 * CD; i += 2048)
        *(uint4*)&wl[i] = *(const uint4*)&Wp[i];
    if constexpr (BN_IN) {
        if (t < 128) {
            float invn = 1.f / (float)n;
            float mu = bnsums[t] * invn;
            float var = bnsums[128 + t] * invn - mu * mu;
            float s = gg[t] * rsqrtf(var + BN_EPS);
            sc[t] = s;
            sh[t] = bb[t] - mu * s;
        }
    }
    __syncthreads();
    int w = t >> 6, l = t & 63;
    int m = l & 15, g = l >> 4;
    int r0 = blockIdx.x * 64;
    int row = r0 + w * 16 + m;
    bool rv = row < n;
    bf16x8 af[4];
#pragma unroll
    for (int ks = 0; ks < 4; ++ks) {
        int c0 = ks * 32 + g * 8;
        float xv[8];
        if constexpr (XBF) {
            uint4 u = make_uint4(0, 0, 0, 0);
            if (rv) u = *(const uint4*)&Xh[(size_t)row * 128 + c0];
            unsigned uu[4] = {u.x, u.y, u.z, u.w};
#pragma unroll
            for (int q = 0; q < 4; ++q) { xv[2 * q] = bfl(uu[q]); xv[2 * q + 1] = bfh(uu[q]); }
        } else {
            float4 x0 = make_float4(0.f, 0.f, 0.f, 0.f), x1 = x0;
            if (rv) {
                x0 = *(const float4*)&Xf[(size_t)row * 128 + c0];
                x1 = *(const float4*)&Xf[(size_t)row * 128 + c0 + 4];
            }
            xv[0] = x0.x; xv[1] = x0.y; xv[2] = x0.z; xv[3] = x0.w;
            xv[4] = x1.x; xv[5] = x1.y; xv[6] = x1.z; xv[7] = x1.w;
        }
        bf16x8 a;
#pragma unroll
        for (int j = 0; j < 8; ++j) {
            float v = xv[j];
            if constexpr (BN_IN) v = fmaxf(0.f, v * sc[c0 + j] + sh[c0 + j]);
            a[j] = (short)f2bf(v);
        }
        af[ks] = a;
    }
    f32x4 acc[NT];
#pragma unroll
    for (int i = 0; i < NT; ++i) acc[i] = (f32x4){0.f, 0.f, 0.f, 0.f};
#pragma unroll
    for (int ks = 0; ks < 4; ++ks) {
#pragma unroll
        for (int nt = 0; nt < NT; ++nt) {
            bf16x8 bfr = *(bf16x8*)&wl[(((nt * 4 + ks) * 64) + l) * 8];
            acc[nt] = __builtin_amdgcn_mfma_f32_16x16x32_bf16(af[ks], bfr, acc[nt], 0, 0, 0);
        }
    }
    float ps[4] = {0.f, 0.f, 0.f, 0.f}, pd[4] = {0.f, 0.f, 0.f, 0.f};
#pragma unroll
    for (int nt = 0; nt < NT; ++nt) {
        float as = a_s[nt * 16 + m], ad = a_d[nt * 16 + m];
#pragma unroll
        for (int r = 0; r < 4; ++r) {
            ps[r] += acc[nt][r] * as;
            pd[r] += acc[nt][r] * ad;
        }
    }
#pragma unroll
    for (int off = 1; off < 16; off <<= 1) {
#pragma unroll
        for (int r = 0; r < 4; ++r) {
            ps[r] += __shfl_xor(ps[r], off);
            pd[r] += __shfl_xor(pd[r], off);
        }
    }
    __syncthreads();
    unsigned short* ot = wl;
#pragma unroll
    for (int nt = 0; nt < NT; ++nt) {
#pragma unroll
        for (int r = 0; r < 4; ++r)
            ot[(w * 16 + g * 4 + r) * CD + nt * 16 + m] = f2bf(acc[nt][r]);
    }
    if (m == 0) {
        int orow = r0 + w * 16 + g * 4;
#pragma unroll
        for (int r = 0; r < 4; ++r) {
            if (orow + r < n) { s_out[orow + r] = ps[r]; d_out[orow + r] = pd[r]; }
        }
    }
    __syncthreads();
    constexpr int CPR = CD / 8;
    for (int c = t; c < 64 * CPR; c += 256) {
        int rr = c / CPR, cc = c % CPR;
        if (r0 + rr < n)
            *(uint4*)&hb[(size_t)(r0 + rr) * CD + cc * 8] = *(uint4*)&ot[rr * CD + cc * 8];
    }
}

// ======== GAT aggregate v5: precomputed coefs, unroll x8 MLP ========
template <int DIM, bool OUT_BF>
__global__ __launch_bounds__(256) void k_agg(
    const unsigned short* __restrict__ hb, const float* __restrict__ wv,
    const int* __restrict__ rowp, const int* __restrict__ csr,
    void* __restrict__ outv, int n) {
    constexpr int LPE = DIM / 8;          // 16 (DIM=128) or 8 (DIM=64)
    int gid = blockIdx.x * blockDim.x + threadIdx.x;
    int wid = gid / LPE;
    int ll = gid & (LPE - 1);
    if (wid >= n) return;
    int beg = rowp[wid], end = rowp[wid + 1];
    const unsigned short* hbl = hb + ll * 8;
    float acc[8] = {};
    float denom = 0.f;
    int e = beg;
    for (; e + 7 < end; e += 8) {
        uint4 p[8];
        float w8[8];
#pragma unroll
        for (int k = 0; k < 8; ++k) {
            int idx = csr[e + k];
            w8[k] = wv[e + k];
            p[k] = *(const uint4*)&hbl[(size_t)idx * DIM];
        }
#pragma unroll
        for (int k = 0; k < 8; ++k) denom += w8[k];
#pragma unroll
        for (int q = 0; q < 4; ++q) {
            unsigned v0[8];
#pragma unroll
            for (int k = 0; k < 8; ++k) v0[k] = (q == 0) ? p[k].x : (q == 1) ? p[k].y : (q == 2) ? p[k].z : p[k].w;
#pragma unroll
            for (int k = 0; k < 8; ++k) {
                acc[2 * q]     += w8[k] * bfl(v0[k]);
                acc[2 * q + 1] += w8[k] * bfh(v0[k]);
            }
        }
    }
    for (; e + 3 < end; e += 4) {
        uint4 p[4];
        float w4[4];
#pragma unroll
        for (int k = 0; k < 4; ++k) {
            int idx = csr[e + k];
            w4[k] = wv[e + k];
            p[k] = *(const uint4*)&hbl[(size_t)idx * DIM];
        }
#pragma unroll
        for (int k = 0; k < 4; ++k) denom += w4[k];
#pragma unroll
        for (int q = 0; q < 4; ++q) {
            unsigned v0[4];
#pragma unroll
            for (int k = 0; k < 4; ++k) v0[k] = (q == 0) ? p[k].x : (q == 1) ? p[k].y : (q == 2) ? p[k].z : p[k].w;
#pragma unroll
            for (int k = 0; k < 4; ++k) {
                acc[2 * q]     += w4[k] * bfl(v0[k]);
                acc[2 * q + 1] += w4[k] * bfh(v0[k]);
            }
        }
    }
    for (; e < end; ++e) {
        int i0 = csr[e];
        float w0 = wv[e];
        uint4 p0 = *(const uint4*)&hbl[(size_t)i0 * DIM];
        unsigned a0[4] = {p0.x, p0.y, p0.z, p0.w};
        denom += w0;
#pragma unroll
        for (int q = 0; q < 4; ++q) {
            acc[2 * q]     += w0 * bfl(a0[q]);
            acc[2 * q + 1] += w0 * bfh(a0[q]);
        }
    }
    float inv = 1.f / denom;
    if constexpr (OUT_BF) {
        unsigned u[4];
#pragma unroll
        for (int q = 0; q < 4; ++q)
            u[q] = (unsigned)f2bf(acc[2 * q] * inv) |
                   ((unsigned)f2bf(acc[2 * q + 1] * inv) << 16);
        *(uint4*)((unsigned short*)outv + (size_t)wid * DIM + ll * 8) =
            make_uint4(u[0], u[1], u[2], u[3]);
    } else {
        float* orow = (float*)outv + (size_t)wid * DIM + ll * 8;
        *(float4*)&orow[0] = make_float4(acc[0] * inv, acc[1] * inv, acc[2] * inv, acc[3] * inv);
        *(float4*)&orow[4] = make_float4(acc[4] * inv, acc[5] * inv, acc[6] * inv, acc[7] * inv);
    }
}

// ======== BatchNorm stats (XBF: bf16 input) ========
template <int CD, bool XBF>
__global__ void k_bn_stats(const void* __restrict__ xv, float* __restrict__ sums, int n) {
    const float* xf = (const float*)xv;
    const unsigned short* xh = (const unsigned short*)xv;
    constexpr int RPB = 256 / CD;
    int t = threadIdx.x;
    int c = t & (CD - 1);
    int rl = t / CD;
    float s = 0.f, sq = 0.f;
    for (int r = blockIdx.x * RPB + rl; r < n; r += gridDim.x * RPB) {
        float v = XBF ? bf2f(xh[(size_t)r * CD + c]) : xf[(size_t)r * CD + c];
        s += v;
        sq += v * v;
    }
    __shared__ float ls[256], lq[256];
    ls[t] = s; lq[t] = sq;
    __syncthreads();
    if (t < CD) {
#pragma unroll
        for (int j = 1; j < RPB; ++j) { s += ls[t + j * CD]; sq += lq[t + j * CD]; }
        atomicAdd(&sums[c], s);
        atomicAdd(&sums[CD + c], sq);
    }
}

template <int CD>
__global__ void k_bn_apply(const float* __restrict__ x, const float* __restrict__ sums,
                           const float* __restrict__ g, const float* __restrict__ b,
                           float* __restrict__ out, int n) {
    size_t i = (size_t)blockIdx.x * blockDim.x + threadIdx.x;
    size_t tot = (size_t)n * CD;
    if (i >= tot) return;
    int c = (int)(i & (CD - 1));
    float invn = 1.f / (float)n;
    float mu = sums[c] * invn;
    float var = sums[CD + c] * invn - mu * mu;
    float v = (x[i] - mu) * rsqrtf(var + BN_EPS) * g[c] + b[c];
    out[i] = fmaxf(v, 0.f);
}

// ======== launch ========
extern "C" void kernel_launch(void* const* d_in, const int* in_sizes, int n_in,
                              void* d_out, int out_size, void* d_ws, size_t ws_size,
                              hipStream_t stream) {
    const float* x   = (const float*)d_in[0];
    const int*   ei  = (const int*)  d_in[1];
    const float* W0  = (const float*)d_in[2];
    const float* as0 = (const float*)d_in[3];
    const float* ad0 = (const float*)d_in[4];
    const float* g0  = (const float*)d_in[5];
    const float* b0  = (const float*)d_in[6];
    const float* W1  = (const float*)d_in[7];
    const float* as1 = (const float*)d_in[8];
    const float* ad1 = (const float*)d_in[9];
    const float* g1  = (const float*)d_in[10];
    const float* b1  = (const float*)d_in[11];
    float* out = (float*)d_out;

    const int N_ = in_sizes[0] / 128;  // 100000
    const int E_ = in_sizes[1] / 2;    // 1600000
    const int TOT = E_ + N_;
    const int nbk = (N_ + 255) >> 8;   // 391 buckets

    // ---- workspace layout (all chunks 8B-aligned) ----
    char* p = (char*)d_ws;
    unsigned short* hb   = (unsigned short*)p; p += (size_t)N_ * 128 * 2;
    unsigned short* aggB = (unsigned short*)p; p += (size_t)N_ * 128 * 2;
    float* agg1 = (float*)p;                   p += (size_t)N_ * 64 * 4;
    int2* bbuf  = (int2*)p;                    p += (size_t)TOT * 8;
    float* s0   = (float*)p;                   p += (size_t)N_ * 4;
    float* d0   = (float*)p;                   p += (size_t)N_ * 4;
    float* bns0 = (float*)p;                   p += 256 * 4;
    float* bns1 = (float*)p;                   p += 128 * 4;
    int* gcnt   = (int*)p;                     p += 512 * 4;
    int* gbase  = (int*)p;                     p += 514 * 4;
    int* gnext  = (int*)p;                     p += 512 * 4;
    int* rowp   = (int*)p;                     p += (size_t)(N_ + 2) * 4;
    int* csr    = (int*)p;                     p += (size_t)TOT * 4;
    int* dste   = (int*)p;                     p += (size_t)TOT * 4;
    float* wv   = (float*)p;                   p += (size_t)TOT * 4;
    unsigned short* Wp0 = (unsigned short*)p;  p += 128 * 128 * 2;
    unsigned short* Wp1 = (unsigned short*)p;  p += 128 * 64 * 2;

    hipMemsetAsync(gcnt, 0, 512 * 4, stream);
    hipMemsetAsync(bns0, 0, 384 * 4, stream);   // bns0 + bns1

    const int gemmBlocks = (N_ + 63) / 64;
    const int aggBlocks128 = (N_ + 15) / 16;
    const int aggBlocks64  = (N_ + 31) / 32;
    const int coefBlocks   = (TOT + 1023) / 1024;
    const int ebBlocks = (TOT + 8191) / 8192;

    // W packing, then GEMM0 (so s0/d0 are ready when k_csr2 computes coefs)
    k_packw2<<<96, 256, 0, stream>>>(W0, W1, Wp0, Wp1);
    k_gemm_mfma<128, false, false><<<gemmBlocks, 256, 0, stream>>>(
        x, Wp0, nullptr, nullptr, nullptr, as0, ad0, hb, s0, d0, N_);

    // CSR build (bucketed) + fused layer-0 coefs
    k_hist<<<ebBlocks, 512, 0, stream>>>(ei, E_, N_, nbk, gcnt);
    k_bscan<<<1, 512, 0, stream>>>(gcnt, gbase, gnext, nbk);
    k_bucket<<<ebBlocks, 512, 0, stream>>>(ei, E_, N_, nbk, gnext, bbuf);
    k_csr2<<<nbk, 256, 0, stream>>>(bbuf, gbase, rowp, csr, dste, s0, d0, wv, N_, nbk);

    // ---- layer 0 ----
    k_agg<128, true><<<aggBlocks128, 256, 0, stream>>>(hb, wv, rowp, csr, aggB, N_);
    k_bn_stats<128, true><<<256, 256, 0, stream>>>(aggB, bns0, N_);

    // ---- layer 1 (BN+ReLU fused into GEMM A-load, bf16 A) ----
    k_gemm_mfma<64, true, true><<<gemmBlocks, 256, 0, stream>>>(
        aggB, Wp1, bns0, g0, b0, as1, ad1, hb, s0, d0, N_);
    k_coef<<<coefBlocks, 256, 0, stream>>>(csr, dste, s0, d0, wv, TOT);
    k_agg<64, false><<<aggBlocks64, 256, 0, stream>>>(hb, wv, rowp, csr, agg1, N_);
    k_bn_stats<64, false><<<256, 256, 0, stream>>>(agg1, bns1, N_);
    k_bn_apply<64><<<(int)(((size_t)N_ * 64 + 255) / 256), 256, 0, stream>>>(
        agg1, bns1, g1, b1, out, N_);
}

// Round 10
// 369.839 us; speedup vs baseline: 1.1495x; 1.1495x over previous
//
#include <hip/hip_runtime.h>
#include <hip/hip_bf16.h>
#include <cmath>

#define BN_EPS 1e-5f
#define SLOPE 0.2f
#define BCAP 6144   // per-bucket chunk capacity (mean 4348, sigma 66 -> 27 sigma)

typedef __attribute__((ext_vector_type(8))) short bf16x8;
typedef __attribute__((ext_vector_type(4))) float f32x4;

__device__ __forceinline__ float lrelu(float x) { return x >= 0.f ? x : SLOPE * x; }
__device__ __forceinline__ float bfl(unsigned u) { return __uint_as_float(u << 16); }
__device__ __forceinline__ float bfh(unsigned u) { return __uint_as_float(u & 0xffff0000u); }
__device__ __forceinline__ float bf2f(unsigned short u) { return __uint_as_float((unsigned)u << 16); }
__device__ __forceinline__ unsigned short f2bf(float f) {
    __hip_bfloat16 h = __float2bfloat16(f);
    return *reinterpret_cast<unsigned short*>(&h);
}

// ======== single-pass bucket scatter (bucket = 256 dst nodes, fixed chunks) ====
__global__ __launch_bounds__(512) void k_bucket(const int* __restrict__ ei, int E, int n,
                                                int nbk, int* __restrict__ gcnt,
                                                int2* __restrict__ bbuf) {
    __shared__ int h[512], off[512];
    int t = threadIdx.x;
    for (int i = t; i < nbk; i += 512) h[i] = 0;
    __syncthreads();
    int base = blockIdx.x * 8192;
    int tot = E + n;
    int srcv[16], dstv[16], rnk[16];
#pragma unroll
    for (int k = 0; k < 16; ++k) {
        int i = base + k * 512 + t;
        dstv[k] = -1;
        if (i < tot) {
            int s_, d_;
            if (i < E) { s_ = ei[i]; d_ = ei[E + i]; }
            else       { s_ = i - E; d_ = s_; }
            srcv[k] = s_; dstv[k] = d_;
            rnk[k] = atomicAdd(&h[d_ >> 8], 1);
        }
    }
    __syncthreads();
    for (int i = t; i < nbk; i += 512)
        if (h[i]) off[i] = atomicAdd(&gcnt[i], h[i]);
    __syncthreads();
#pragma unroll
    for (int k = 0; k < 16; ++k) {
        int d_ = dstv[k];
        if (d_ >= 0) {
            int b = d_ >> 8;
            bbuf[(size_t)b * BCAP + off[b] + rnk[k]] = make_int2(srcv[k], d_);
        }
    }
}

// ======== scan bucket counts -> global bases (nbk <= 512, one block) ========
__global__ __launch_bounds__(512) void k_bscan(const int* __restrict__ gcnt,
                                               int* __restrict__ gbase, int nbk) {
    __shared__ int tmp[512];
    int t = threadIdx.x;
    int v = (t < nbk) ? gcnt[t] : 0;
    tmp[t] = v;
    __syncthreads();
    for (int off = 1; off < 512; off <<= 1) {
        int a = (t >= off) ? tmp[t - off] : 0;
        __syncthreads();
        tmp[t] += a;
        __syncthreads();
    }
    int ex = tmp[t] - v;
    if (t < nbk) gbase[t] = ex;
    if (t == nbk - 1) gbase[nbk] = tmp[t];
}

// ======== per-bucket counting sort -> rowp + csr (src only) ========
__global__ __launch_bounds__(256) void k_csr2(const int2* __restrict__ bbuf,
                                              const int* __restrict__ gcnt,
                                              const int* __restrict__ gbase,
                                              int* __restrict__ rowp, int* __restrict__ csr,
                                              int n, int nbk) {
    __shared__ int cnt[256], scn[256];
    int b = blockIdx.x;
    int t = threadIdx.x;
    int cntb = gcnt[b];
    int gb = gbase[b];
    const int2* bb = bbuf + (size_t)b * BCAP;
    int node0 = b << 8;
    cnt[t] = 0;
    __syncthreads();
    for (int i = t; i < cntb; i += 256)
        atomicAdd(&cnt[bb[i].y & 255], 1);
    __syncthreads();
    int v = cnt[t];
    scn[t] = v;
    __syncthreads();
    for (int off = 1; off < 256; off <<= 1) {
        int a = (t >= off) ? scn[t - off] : 0;
        __syncthreads();
        scn[t] += a;
        __syncthreads();
    }
    int ex = scn[t] - v;
    if (node0 + t < n) rowp[node0 + t] = gb + ex;
    if (b == nbk - 1 && t == 0) rowp[n] = gb + cntb;
    cnt[t] = ex;
    __syncthreads();
    for (int i = t; i < cntb; i += 256) {
        int2 e = bb[i];
        int pos = atomicAdd(&cnt[e.y & 255], 1);
        csr[gb + pos] = e.x;
    }
}

// ======== pack W0[128x128] + W1[128x64] fp32 -> bf16 B-fragment order ========
__global__ void k_packw2(const float* __restrict__ W0, const float* __restrict__ W1,
                         unsigned short* __restrict__ Wp0, unsigned short* __restrict__ Wp1) {
    int idx = blockIdx.x * 256 + threadIdx.x;
    if (idx < 128 * 128) {
        int k = idx >> 7, nG = idx & 127;
        int nt = nG >> 4, nn = nG & 15, ks = k >> 5, g = (k >> 3) & 3, j = k & 7;
        Wp0[(((nt * 4 + ks) * 64) + g * 16 + nn) * 8 + j] = f2bf(W0[idx]);
    } else {
        int i2 = idx - 128 * 128;
        if (i2 < 128 * 64) {
            int k = i2 >> 6, nG = i2 & 63;
            int nt = nG >> 4, nn = nG & 15, ks = k >> 5, g = (k >> 3) & 3, j = k & 7;
            Wp1[(((nt * 4 + ks) * 64) + g * 16 + nn) * 8 + j] = f2bf(W1[i2]);
        }
    }
}

// ======== MFMA GEMM: h = act(X)@W, bf16 h out, s/d scores fused ========
template <int CD, bool BN_IN, bool XBF>
__global__ __launch_bounds__(256) void k_gemm_mfma(
    const void* __restrict__ Xv, const unsigned short* __restrict__ Wp,
    const float* __restrict__ bnsums, const float* __restrict__ gg,
    const float* __restrict__ bb, const float* __restrict__ a_s,
    const float* __restrict__ a_d, unsigned short* __restrict__ hb,
    float* __restrict__ s_out, float* __restrict__ d_out, int n) {
    constexpr int NT = CD / 16;
    const float* Xf = (const float*)Xv;
    const unsigned short* Xh = (const unsigned short*)Xv;
    __shared__ unsigned short wl[128 * CD];
    __shared__ float sc[128], sh[128];
    int t = threadIdx.x;
    for (int i = t * 8; i < 128 * CD; i += 2048)
        *(uint4*)&wl[i] = *(const uint4*)&Wp[i];
    if constexpr (BN_IN) {
        if (t < 128) {
            float invn = 1.f / (float)n;
            float mu = bnsums[t] * invn;
            float var = bnsums[128 + t] * invn - mu * mu;
            float s = gg[t] * rsqrtf(var + BN_EPS);
            sc[t] = s;
            sh[t] = bb[t] - mu * s;
        }
    }
    __syncthreads();
    int w = t >> 6, l = t & 63;
    int m = l & 15, g = l >> 4;
    int r0 = blockIdx.x * 64;
    int row = r0 + w * 16 + m;
    bool rv = row < n;
    bf16x8 af[4];
#pragma unroll
    for (int ks = 0; ks < 4; ++ks) {
        int c0 = ks * 32 + g * 8;
        float xv[8];
        if constexpr (XBF) {
            uint4 u = make_uint4(0, 0, 0, 0);
            if (rv) u = *(const uint4*)&Xh[(size_t)row * 128 + c0];
            unsigned uu[4] = {u.x, u.y, u.z, u.w};
#pragma unroll
            for (int q = 0; q < 4; ++q) { xv[2 * q] = bfl(uu[q]); xv[2 * q + 1] = bfh(uu[q]); }
        } else {
            float4 x0 = make_float4(0.f, 0.f, 0.f, 0.f), x1 = x0;
            if (rv) {
                x0 = *(const float4*)&Xf[(size_t)row * 128 + c0];
                x1 = *(const float4*)&Xf[(size_t)row * 128 + c0 + 4];
            }
            xv[0] = x0.x; xv[1] = x0.y; xv[2] = x0.z; xv[3] = x0.w;
            xv[4] = x1.x; xv[5] = x1.y; xv[6] = x1.z; xv[7] = x1.w;
        }
        bf16x8 a;
#pragma unroll
        for (int j = 0; j < 8; ++j) {
            float v = xv[j];
            if constexpr (BN_IN) v = fmaxf(0.f, v * sc[c0 + j] + sh[c0 + j]);
            a[j] = (short)f2bf(v);
        }
        af[ks] = a;
    }
    f32x4 acc[NT];
#pragma unroll
    for (int i = 0; i < NT; ++i) acc[i] = (f32x4){0.f, 0.f, 0.f, 0.f};
#pragma unroll
    for (int ks = 0; ks < 4; ++ks) {
#pragma unroll
        for (int nt = 0; nt < NT; ++nt) {
            bf16x8 bfr = *(bf16x8*)&wl[(((nt * 4 + ks) * 64) + l) * 8];
            acc[nt] = __builtin_amdgcn_mfma_f32_16x16x32_bf16(af[ks], bfr, acc[nt], 0, 0, 0);
        }
    }
    float ps[4] = {0.f, 0.f, 0.f, 0.f}, pd[4] = {0.f, 0.f, 0.f, 0.f};
#pragma unroll
    for (int nt = 0; nt < NT; ++nt) {
        float as = a_s[nt * 16 + m], ad = a_d[nt * 16 + m];
#pragma unroll
        for (int r = 0; r < 4; ++r) {
            ps[r] += acc[nt][r] * as;
            pd[r] += acc[nt][r] * ad;
        }
    }
#pragma unroll
    for (int off = 1; off < 16; off <<= 1) {
#pragma unroll
        for (int r = 0; r < 4; ++r) {
            ps[r] += __shfl_xor(ps[r], off);
            pd[r] += __shfl_xor(pd[r], off);
        }
    }
    __syncthreads();
    unsigned short* ot = wl;
#pragma unroll
    for (int nt = 0; nt < NT; ++nt) {
#pragma unroll
        for (int r = 0; r < 4; ++r)
            ot[(w * 16 + g * 4 + r) * CD + nt * 16 + m] = f2bf(acc[nt][r]);
    }
    if (m == 0) {
        int orow = r0 + w * 16 + g * 4;
#pragma unroll
        for (int r = 0; r < 4; ++r) {
            if (orow + r < n) { s_out[orow + r] = ps[r]; d_out[orow + r] = pd[r]; }
        }
    }
    __syncthreads();
    constexpr int CPR = CD / 8;
    for (int c = t; c < 64 * CPR; c += 256) {
        int rr = c / CPR, cc = c % CPR;
        if (r0 + rr < n)
            *(uint4*)&hb[(size_t)(r0 + rr) * CD + cc * 8] = *(uint4*)&ot[rr * CD + cc * 8];
    }
}

// ======== GAT aggregate v6: inline coef, per-node groups, 2-stage pipeline ====
// Iteration k prefetches quad k+1's csr+s (hiding the csr->s->exp chain under
// the 4 independent hb gathers of quad k). No precomputed-coef plumbing.
template <int DIM, bool OUT_BF>
__global__ __launch_bounds__(256) void k_agg(
    const unsigned short* __restrict__ hb, const float* __restrict__ s,
    const float* __restrict__ d, const int* __restrict__ rowp,
    const int* __restrict__ csr, void* __restrict__ outv, int n) {
    constexpr int LPE = DIM / 8;          // 16 (DIM=128) or 8 (DIM=64)
    int gid = blockIdx.x * blockDim.x + threadIdx.x;
    int wid = gid / LPE;
    int ll = gid & (LPE - 1);
    if (wid >= n) return;
    int beg = rowp[wid], end = rowp[wid + 1];
    float dv = d[wid];
    const unsigned short* hbl = hb + ll * 8;
    float acc[8] = {};
    float denom = 0.f;
    int e = beg;
    if (e + 3 < end) {
        int lim = end - 1;
        int i0 = csr[e], i1 = csr[e + 1], i2 = csr[e + 2], i3 = csr[e + 3];
        float s0 = s[i0], s1 = s[i1], s2 = s[i2], s3 = s[i3];
        while (true) {
            int en = e + 4;
            // prefetch next quad (clamped; wasted on last iteration)
            int c0 = en < lim ? en : lim;
            int c1 = en + 1 < lim ? en + 1 : lim;
            int c2 = en + 2 < lim ? en + 2 : lim;
            int c3 = en + 3 < lim ? en + 3 : lim;
            int j0 = csr[c0], j1 = csr[c1], j2 = csr[c2], j3 = csr[c3];
            float t0 = s[j0], t1 = s[j1], t2 = s[j2], t3 = s[j3];
            // current quad's independent hb gathers
            uint4 p0 = *(const uint4*)&hbl[(size_t)i0 * DIM];
            uint4 p1 = *(const uint4*)&hbl[(size_t)i1 * DIM];
            uint4 p2 = *(const uint4*)&hbl[(size_t)i2 * DIM];
            uint4 p3 = *(const uint4*)&hbl[(size_t)i3 * DIM];
            float w0 = __expf(lrelu(s0 + dv));
            float w1 = __expf(lrelu(s1 + dv));
            float w2 = __expf(lrelu(s2 + dv));
            float w3 = __expf(lrelu(s3 + dv));
            denom += (w0 + w1) + (w2 + w3);
            unsigned a0[4] = {p0.x, p0.y, p0.z, p0.w};
            unsigned a1[4] = {p1.x, p1.y, p1.z, p1.w};
            unsigned a2[4] = {p2.x, p2.y, p2.z, p2.w};
            unsigned a3[4] = {p3.x, p3.y, p3.z, p3.w};
#pragma unroll
            for (int q = 0; q < 4; ++q) {
                acc[2 * q]     += w0 * bfl(a0[q]) + w1 * bfl(a1[q]) + w2 * bfl(a2[q]) + w3 * bfl(a3[q]);
                acc[2 * q + 1] += w0 * bfh(a0[q]) + w1 * bfh(a1[q]) + w2 * bfh(a2[q]) + w3 * bfh(a3[q]);
            }
            e = en;
            if (e + 3 >= end) break;
            i0 = j0; i1 = j1; i2 = j2; i3 = j3;
            s0 = t0; s1 = t1; s2 = t2; s3 = t3;
        }
    }
    for (; e < end; ++e) {
        int i0 = csr[e];
        float w0 = __expf(lrelu(s[i0] + dv));
        uint4 p0 = *(const uint4*)&hbl[(size_t)i0 * DIM];
        unsigned a0[4] = {p0.x, p0.y, p0.z, p0.w};
        denom += w0;
#pragma unroll
        for (int q = 0; q < 4; ++q) {
            acc[2 * q]     += w0 * bfl(a0[q]);
            acc[2 * q + 1] += w0 * bfh(a0[q]);
        }
    }
    float inv = 1.f / denom;
    if constexpr (OUT_BF) {
        unsigned u[4];
#pragma unroll
        for (int q = 0; q < 4; ++q)
            u[q] = (unsigned)f2bf(acc[2 * q] * inv) |
                   ((unsigned)f2bf(acc[2 * q + 1] * inv) << 16);
        *(uint4*)((unsigned short*)outv + (size_t)wid * DIM + ll * 8) =
            make_uint4(u[0], u[1], u[2], u[3]);
    } else {
        float* orow = (float*)outv + (size_t)wid * DIM + ll * 8;
        *(float4*)&orow[0] = make_float4(acc[0] * inv, acc[1] * inv, acc[2] * inv, acc[3] * inv);
        *(float4*)&orow[4] = make_float4(acc[4] * inv, acc[5] * inv, acc[6] * inv, acc[7] * inv);
    }
}

// ======== BatchNorm stats (XBF: bf16 input) ========
template <int CD, bool XBF>
__global__ void k_bn_stats(const void* __restrict__ xv, float* __restrict__ sums, int n) {
    const float* xf = (const float*)xv;
    const unsigned short* xh = (const unsigned short*)xv;
    constexpr int RPB = 256 / CD;
    int t = threadIdx.x;
    int c = t & (CD - 1);
    int rl = t / CD;
    float s = 0.f, sq = 0.f;
    for (int r = blockIdx.x * RPB + rl; r < n; r += gridDim.x * RPB) {
        float v = XBF ? bf2f(xh[(size_t)r * CD + c]) : xf[(size_t)r * CD + c];
        s += v;
        sq += v * v;
    }
    __shared__ float ls[256], lq[256];
    ls[t] = s; lq[t] = sq;
    __syncthreads();
    if (t < CD) {
#pragma unroll
        for (int j = 1; j < RPB; ++j) { s += ls[t + j * CD]; sq += lq[t + j * CD]; }
        atomicAdd(&sums[c], s);
        atomicAdd(&sums[CD + c], sq);
    }
}

template <int CD>
__global__ void k_bn_apply(const float* __restrict__ x, const float* __restrict__ sums,
                           const float* __restrict__ g, const float* __restrict__ b,
                           float* __restrict__ out, int n) {
    size_t i = (size_t)blockIdx.x * blockDim.x + threadIdx.x;
    size_t tot = (size_t)n * CD;
    if (i >= tot) return;
    int c = (int)(i & (CD - 1));
    float invn = 1.f / (float)n;
    float mu = sums[c] * invn;
    float var = sums[CD + c] * invn - mu * mu;
    float v = (x[i] - mu) * rsqrtf(var + BN_EPS) * g[c] + b[c];
    out[i] = fmaxf(v, 0.f);
}

// ======== launch ========
extern "C" void kernel_launch(void* const* d_in, const int* in_sizes, int n_in,
                              void* d_out, int out_size, void* d_ws, size_t ws_size,
                              hipStream_t stream) {
    const float* x   = (const float*)d_in[0];
    const int*   ei  = (const int*)  d_in[1];
    const float* W0  = (const float*)d_in[2];
    const float* as0 = (const float*)d_in[3];
    const float* ad0 = (const float*)d_in[4];
    const float* g0  = (const float*)d_in[5];
    const float* b0  = (const float*)d_in[6];
    const float* W1  = (const float*)d_in[7];
    const float* as1 = (const float*)d_in[8];
    const float* ad1 = (const float*)d_in[9];
    const float* g1  = (const float*)d_in[10];
    const float* b1  = (const float*)d_in[11];
    float* out = (float*)d_out;

    const int N_ = in_sizes[0] / 128;  // 100000
    const int E_ = in_sizes[1] / 2;    // 1600000
    const int TOT = E_ + N_;
    const int nbk = (N_ + 255) >> 8;   // 391 buckets

    // ---- workspace layout (all chunks 8B-aligned) ----
    char* p = (char*)d_ws;
    unsigned short* hb   = (unsigned short*)p; p += (size_t)N_ * 128 * 2;
    unsigned short* aggB = (unsigned short*)p; p += (size_t)N_ * 128 * 2;
    float* agg1 = (float*)p;                   p += (size_t)N_ * 64 * 4;
    int2* bbuf  = (int2*)p;                    p += (size_t)nbk * BCAP * 8;
    float* s0   = (float*)p;                   p += (size_t)N_ * 4;
    float* d0   = (float*)p;                   p += (size_t)N_ * 4;
    float* bns0 = (float*)p;                   p += 256 * 4;
    float* bns1 = (float*)p;                   p += 128 * 4;
    int* gcnt   = (int*)p;                     p += 512 * 4;
    int* gbase  = (int*)p;                     p += 514 * 4;
    int* rowp   = (int*)p;                     p += (size_t)(N_ + 2) * 4;
    int* csr    = (int*)p;                     p += (size_t)TOT * 4;
    unsigned short* Wp0 = (unsigned short*)p;  p += 128 * 128 * 2;
    unsigned short* Wp1 = (unsigned short*)p;  p += 128 * 64 * 2;

    hipMemsetAsync(gcnt, 0, 512 * 4, stream);
    hipMemsetAsync(bns0, 0, 384 * 4, stream);   // bns0 + bns1

    const int gemmBlocks = (N_ + 63) / 64;
    const int aggBlocks128 = (N_ + 15) / 16;
    const int aggBlocks64  = (N_ + 31) / 32;
    const int ebBlocks = (TOT + 8191) / 8192;

    // W packing + GEMM0
    k_packw2<<<96, 256, 0, stream>>>(W0, W1, Wp0, Wp1);
    k_gemm_mfma<128, false, false><<<gemmBlocks, 256, 0, stream>>>(
        x, Wp0, nullptr, nullptr, nullptr, as0, ad0, hb, s0, d0, N_);

    // CSR build: single-pass bucket scatter -> scan -> per-bucket sort
    k_bucket<<<ebBlocks, 512, 0, stream>>>(ei, E_, N_, nbk, gcnt, bbuf);
    k_bscan<<<1, 512, 0, stream>>>(gcnt, gbase, nbk);
    k_csr2<<<nbk, 256, 0, stream>>>(bbuf, gcnt, gbase, rowp, csr, N_, nbk);

    // ---- layer 0 ----
    k_agg<128, true><<<aggBlocks128, 256, 0, stream>>>(hb, s0, d0, rowp, csr, aggB, N_);
    k_bn_stats<128, true><<<256, 256, 0, stream>>>(aggB, bns0, N_);

    // ---- layer 1 (BN+ReLU fused into GEMM A-load, bf16 A) ----
    k_gemm_mfma<64, true, true><<<gemmBlocks, 256, 0, stream>>>(
        aggB, Wp1, bns0, g0, b0, as1, ad1, hb, s0, d0, N_);
    k_agg<64, false><<<aggBlocks64, 256, 0, stream>>>(hb, s0, d0, rowp, csr, agg1, N_);
    k_bn_stats<64, false><<<256, 256, 0, stream>>>(agg1, bns1, N_);
    k_bn_apply<64><<<(int)(((size_t)N_ * 64 + 255) / 256), 256, 0, stream>>>(
        agg1, bns1, g1, b1, out, N_);
}